// Round 17
// baseline (166.556 us; speedup 1.0000x reference)
//
#include <hip/hip_runtime.h>

typedef unsigned long long u64;
typedef unsigned int u32;

#define R_TOT 159882
#define POST 1000
#define IMG_SZ 800.0f
#define NMS_TH 0.7f
#define BBOX_CLIP 4.135166556742356f
#define LCAP 1024

__device__ __forceinline__ float fadd_(float a, float b){ return __fadd_rn(a,b); }
__device__ __forceinline__ float fsub_(float a, float b){ return __fsub_rn(a,b); }
__device__ __forceinline__ float fmul_(float a, float b){ return __fmul_rn(a,b); }

__device__ __forceinline__ int lvl_len(int l){ const int L[5]={120000,30000,7500,1875,507}; return L[l]; }
__device__ __forceinline__ int lvl_off(int l){ const int L[5]={0,120000,150000,157500,159375}; return L[l]; }
__device__ __forceinline__ int lvl_k(int l){ const int L[5]={1000,1000,1000,1000,507}; return L[l]; }

__device__ __forceinline__ u32 mono_(u32 u){ return (u & 0x80000000u) ? ~u : (u | 0x80000000u); }

__device__ __forceinline__ u64 readlane64(u64 v, int i){
  u32 lo = (u32)__builtin_amdgcn_readlane((int)(u32)v, i);
  u32 hi = (u32)__builtin_amdgcn_readlane((int)(u32)(v >> 32), i);
  return ((u64)hi << 32) | (u64)lo;
}

// ---------- 1. k_front: per-slice hist (also published for the exact pick)
//    + LOCAL pick + collect (r16-verbatim). ----------
__global__ __launch_bounds__(256) void k_front(const float* __restrict__ obj,
                                               int* histS,
                                               u64* mainS, u64* tieS,
                                               int* cntS, int* cnt2S){
  int g = blockIdx.x, sl = blockIdx.y;
  int img = g/5, lvl = g%5;
  int n = lvl_len(lvl), s0 = lvl_off(lvl), k = lvl_k(lvl);
  int tid = threadIdx.x, lane = tid & 63, wid = tid >> 6;
  __shared__ __align__(16) int lh[4096];
  __shared__ int wsum[4];
  __shared__ int sh_bs, lc, lc2;
  for (int i = tid; i < 4096; i += 256) lh[i] = 0;
  __syncthreads();
  int lo = (int)((long long)n * sl / 16), hiS = (int)((long long)n * (sl+1) / 16);
  int ns = hiS - lo;
  int ks = k < ns ? k : ns;
  const float* p = obj + img*R_TOT + s0;
  #pragma unroll 4
  for (int e = lo + tid; e < hiS; e += 256){
    u32 mu = mono_(__float_as_uint(p[e]));
    atomicAdd(&lh[(~mu) >> 20], 1);
  }
  __syncthreads();
  {
    int* dst = histS + (g*16 + sl)*4096;
    for (int i = tid; i < 4096; i += 256) dst[i] = lh[i];
  }
  int h[16];
  #pragma unroll
  for (int j = 0; j < 16; j++) h[j] = lh[16*tid + j];
  int part = 0;
  #pragma unroll
  for (int j = 0; j < 16; j++) part += h[j];
  int x = part;
  for (int d = 1; d < 64; d <<= 1){ int y = __shfl_up(x, d); if (lane >= d) x += y; }
  if (lane == 63) wsum[wid] = x;
  if (tid == 0){ lc = 0; lc2 = 0; }
  __syncthreads();
  int add = 0;
  for (int w = 0; w < wid; w++) add += wsum[w];
  int incl = x + add, excl = incl - part;
  if (excl < ks && ks <= incl){
    int cum = excl;
    #pragma unroll
    for (int q = 0; q < 16; q++){
      if (cum + h[q] >= ks){ sh_bs = 16*tid + q; break; }
      cum += h[q];
    }
  }
  __syncthreads();
  int bs = sh_bs;
  u64* lmain = (u64*)lh;            // [0, 8K)
  u64* ltie  = (u64*)lh + 1024;     // [8K, 16K)
  #pragma unroll 4
  for (int e = lo + tid; e < hiS; e += 256){
    u32 mu = mono_(__float_as_uint(p[e]));
    u64 key56 = (((u64)(~mu)) << 24) | (u32)(s0 + e);
    int bin = (int)(key56 >> 44);
    if (bin < bs){ int pos = atomicAdd(&lc, 1); lmain[pos] = key56; }      // <= ks-1 <= 999
    else if (bin == bs){ int pos = atomicAdd(&lc2, 1); if (pos < 1024) ltie[pos] = key56; }
  }
  __syncthreads();
  int idx16 = g*16 + sl;
  if (tid == 0){ cntS[idx16] = lc; cnt2S[idx16] = lc2; }
  for (int i = tid; i < lc; i += 256) mainS[idx16*1024 + i] = lmain[i];
  int c2l = lc2 < 1024 ? lc2 : 1024;
  for (int i = tid; i < c2l; i += 256) tieS[idx16*1024 + i] = ltie[i];
}

// ---------- 2. seldecode: exact pick from summed slice hists + wave-per-slice gather
//    + SUB-HISTOGRAM tie refine (O(c) not O(c^2)) + SPARSE-BARRIER bitonic + decode. ----------
__global__ __launch_bounds__(1024) void k_seldecode(const float* __restrict__ obj,
                                                    const float4* __restrict__ deltas,
                                                    const float4* __restrict__ anchors,
                                                    const int* __restrict__ histS,
                                                    const u64* __restrict__ mainS,
                                                    const u64* __restrict__ tieS,
                                                    const int* __restrict__ cntS,
                                                    const int* __restrict__ cnt2S,
                                                    float4* boxL, float* scoreL,
                                                    float4* nbox, u64* okeyN, int* ncnt){
  int g = blockIdx.x, img = g/5, lvl = g%5;
  int s0 = lvl_off(lvl), n = lvl_len(lvl), k = lvl_k(lvl);
  const float* p = obj + img*R_TOT + s0;
  __shared__ u64 Lbuf[LCAP];
  __shared__ u64 mainL[1024];
  __shared__ __align__(16) float4 lbox[1024];   // reused: sub-hist / fallback hist
  __shared__ u64 lokey[1024];                   // reused: sub-tie buffer
  __shared__ unsigned char lval[1024];
  __shared__ int h16[16];
  __shared__ int scnt[16], tcnt[16];
  __shared__ int wsum16[16];
  __shared__ int sh_bs, sh_rem, sh_mc, sh_tc, sh_sc, sh_rem2, sh_ovf;
  __shared__ int sh_bs2, sh_rem2b, sh_c3;
  __shared__ u64 sh_thr;
  int tid = threadIdx.x, lane = tid & 63, wid = tid >> 6;
  if (tid < 16){ scnt[tid] = cntS[g*16 + tid]; tcnt[tid] = cnt2S[g*16 + tid]; }
  mainL[tid] = ~0ull;
  __syncthreads();
  if (tid == 0){
    int o = 0;
    #pragma unroll
    for (int q = 0; q < 16; q++) if (tcnt[q] > 1024) o = 1;
    sh_ovf = o; sh_mc = 0; sh_tc = 0; sh_sc = 0; sh_c3 = 0;
  }
  // --- exact global pick: sum 16 slice histograms, 4 bins/thread (no atomics) ---
  int h0 = 0, h1 = 0, h2 = 0, h3 = 0;
  {
    const int* hb = histS + g*16*4096 + 4*tid;
    #pragma unroll
    for (int s2 = 0; s2 < 16; s2++){
      int4 a = *(const int4*)(hb + s2*4096);
      h0 += a.x; h1 += a.y; h2 += a.z; h3 += a.w;
    }
  }
  int part = h0 + h1 + h2 + h3;
  int x = part;
  for (int d = 1; d < 64; d <<= 1){ int y = __shfl_up(x, d); if (lane >= d) x += y; }
  if (lane == 63) wsum16[wid] = x;
  __syncthreads();
  int add = 0;
  for (int w = 0; w < wid; w++) add += wsum16[w];
  int incl = x + add, excl = incl - part;
  if (excl < k && k <= incl){
    int cum = excl;
    if (cum + h0 >= k){ sh_bs = 4*tid;   sh_rem = k - cum; }
    else { cum += h0;
      if (cum + h1 >= k){ sh_bs = 4*tid+1; sh_rem = k - cum; }
      else { cum += h1;
        if (cum + h2 >= k){ sh_bs = 4*tid+2; sh_rem = k - cum; }
        else { cum += h2;    sh_bs = 4*tid+3; sh_rem = k - cum; }
      }
    }
  }
  __syncthreads();
  int bs = sh_bs;
  if (!sh_ovf){
    // --- single candidate gather: wave-per-slice, clamped-address 4-deep batching ---
    int mc = scnt[wid];
    int tcc = tcnt[wid] < 1024 ? tcnt[wid] : 1024;
    const u64* msrc = mainS + ((size_t)(g*16 + wid))*1024;
    const u64* tsrc = tieS + ((size_t)(g*16 + wid))*1024;
    for (int base = 0; base < mc; base += 256){
      int i0 = base + lane;
      u64 v0 = msrc[(i0       < mc) ? i0       : 0];
      u64 v1 = msrc[(i0+64    < mc) ? i0+64    : 0];
      u64 v2 = msrc[(i0+128   < mc) ? i0+128   : 0];
      u64 v3 = msrc[(i0+192   < mc) ? i0+192   : 0];
      #define PUSH(cond, vv) if (cond){ int b_ = (int)((vv) >> 44); \
        if (b_ < bs){ int pos = atomicAdd(&sh_mc, 1); mainL[pos] = (vv); } \
        else if (b_ == bs){ int pos = atomicAdd(&sh_tc, 1); if (pos < LCAP) Lbuf[pos] = (vv); } }
      PUSH(i0 < mc, v0) PUSH(i0+64 < mc, v1) PUSH(i0+128 < mc, v2) PUSH(i0+192 < mc, v3)
    }
    for (int base = 0; base < tcc; base += 256){
      int i0 = base + lane;
      u64 v0 = tsrc[(i0       < tcc) ? i0       : 0];
      u64 v1 = tsrc[(i0+64    < tcc) ? i0+64    : 0];
      u64 v2 = tsrc[(i0+128   < tcc) ? i0+128   : 0];
      u64 v3 = tsrc[(i0+192   < tcc) ? i0+192   : 0];
      PUSH(i0 < tcc, v0) PUSH(i0+64 < tcc, v1) PUSH(i0+128 < tcc, v2) PUSH(i0+192 < tcc, v3)
      #undef PUSH
    }
    __syncthreads();
    int nb = sh_mc, c2r = sh_tc, rem = sh_rem;
    if (c2r <= LCAP){
      // --- sub-histogram tie refine on bits 43..32 (exact; keys unique) ---
      int* chist = (int*)lbox;
      for (int i = tid; i < 4096; i += 1024) chist[i] = 0;
      __syncthreads();
      for (int e = tid; e < c2r; e += 1024){
        u64 kk = Lbuf[e];
        atomicAdd(&chist[(int)((kk >> 32) & 0xFFFu)], 1);
      }
      __syncthreads();
      int t0 = chist[4*tid], t1 = chist[4*tid+1], t2 = chist[4*tid+2], t3 = chist[4*tid+3];
      int tpart = t0 + t1 + t2 + t3;
      int tx = tpart;
      for (int d = 1; d < 64; d <<= 1){ int y = __shfl_up(tx, d); if (lane >= d) tx += y; }
      if (lane == 63) wsum16[wid] = tx;
      __syncthreads();
      int tadd = 0;
      for (int w = 0; w < wid; w++) tadd += wsum16[w];
      int tincl = tx + tadd, texcl = tincl - tpart;
      if (texcl < rem && rem <= tincl){
        int cum = texcl;
        if (cum + t0 >= rem){ sh_bs2 = 4*tid;   sh_rem2b = rem - cum; }
        else { cum += t0;
          if (cum + t1 >= rem){ sh_bs2 = 4*tid+1; sh_rem2b = rem - cum; }
          else { cum += t1;
            if (cum + t2 >= rem){ sh_bs2 = 4*tid+2; sh_rem2b = rem - cum; }
            else { cum += t2;    sh_bs2 = 4*tid+3; sh_rem2b = rem - cum; }
          }
        }
      }
      __syncthreads();
      int bs2 = sh_bs2;
      u64* subT = lokey;
      for (int e = tid; e < c2r; e += 1024){
        u64 kk = Lbuf[e];
        int sb2 = (int)((kk >> 32) & 0xFFFu);
        if (sb2 < bs2){ int p2 = atomicAdd(&sh_sc, 1); mainL[nb + p2] = kk; }
        else if (sb2 == bs2){ int p3 = atomicAdd(&sh_c3, 1); subT[p3] = kk; }
      }
      __syncthreads();
      int c3 = sh_c3, rem2b = sh_rem2b;
      for (int e = tid; e < c3; e += 1024){
        u64 kk = subT[e];
        int rk = 0;
        for (int qq = 0; qq < c3; qq++) rk += (subT[qq] < kk) ? 1 : 0;
        if (rk < rem2b){ int p2 = atomicAdd(&sh_sc, 1); mainL[nb + p2] = kk; }
      }
    } else {
      if (tid == 0) sh_ovf = 1;
    }
    __syncthreads();
  }
  if (sh_ovf){
    // ---- FULL FALLBACK from obj (never hit on bench data): hist + pick + refine ----
    int* fh = (int*)lbox;
    for (int i = tid; i < 4096; i += 1024) fh[i] = 0;
    if (tid == 0){ sh_mc = 0; sh_sc = 0; }
    __syncthreads();
    for (int e = tid; e < n; e += 1024){
      u32 mu = mono_(__float_as_uint(p[e]));
      atomicAdd(&fh[(int)((~mu) >> 20)], 1);
    }
    __syncthreads();
    int f0 = fh[4*tid], f1 = fh[4*tid+1], f2 = fh[4*tid+2], f3 = fh[4*tid+3];
    int fpart = f0 + f1 + f2 + f3;
    int fx = fpart;
    for (int d = 1; d < 64; d <<= 1){ int y = __shfl_up(fx, d); if (lane >= d) fx += y; }
    if (lane == 63) wsum16[wid] = fx;
    __syncthreads();
    int fadd2 = 0;
    for (int w = 0; w < wid; w++) fadd2 += wsum16[w];
    int fincl = fx + fadd2, fexcl = fincl - fpart;
    if (fexcl < k && k <= fincl){
      int cum = fexcl;
      if (cum + f0 >= k){ sh_bs = 4*tid;   sh_rem = k - cum; }
      else { cum += f0;
        if (cum + f1 >= k){ sh_bs = 4*tid+1; sh_rem = k - cum; }
        else { cum += f1;
          if (cum + f2 >= k){ sh_bs = 4*tid+2; sh_rem = k - cum; }
          else { cum += f2;    sh_bs = 4*tid+3; sh_rem = k - cum; }
        }
      }
    }
    mainL[tid] = ~0ull;
    __syncthreads();
    int fbs = sh_bs;
    for (int e = tid; e < n; e += 1024){
      u32 mu = mono_(__float_as_uint(p[e]));
      u64 kk = (((u64)(~mu)) << 24) | (u32)(s0 + e);
      if ((int)(kk >> 44) < fbs){ int pos = atomicAdd(&sh_mc, 1); mainL[pos] = kk; }
    }
    __syncthreads();
    int nb = sh_mc;
    if (tid == 0){ sh_thr = ((u64)fbs) << 44; sh_rem2 = sh_rem; }
    __syncthreads();
    for (int shift = 40; shift >= 0; shift -= 4){
      if (tid < 16) h16[tid] = 0;
      __syncthreads();
      u64 pref = sh_thr;
      u64 himask = ~((1ull << (shift+4)) - 1ull);
      for (int e = tid; e < n; e += 1024){
        u32 mu = mono_(__float_as_uint(p[e]));
        u64 kk = (((u64)(~mu)) << 24) | (u32)(s0 + e);
        if ((kk & himask) == (pref & himask)) atomicAdd(&h16[(int)((kk >> shift) & 15)], 1);
      }
      __syncthreads();
      if (tid == 0){
        int r2 = sh_rem2, cum = 0;
        for (int d = 0; d < 16; d++){
          int hb2 = h16[d];
          if (cum + hb2 >= r2){ sh_thr = pref | ((u64)d << shift); sh_rem2 = r2 - cum; break; }
          cum += hb2;
        }
      }
      __syncthreads();
    }
    u64 thr = sh_thr;
    for (int e = tid; e < n; e += 1024){
      u32 mu = mono_(__float_as_uint(p[e]));
      u64 kk = (((u64)(~mu)) << 24) | (u32)(s0 + e);
      if ((int)(kk >> 44) == fbs && kk <= thr){ int p2 = atomicAdd(&sh_sc, 1); mainL[nb + p2] = kk; }
    }
    __syncthreads();
  }
  // --- SPARSE-BARRIER bitonic sort 1024: j<64 partners stay inside one wave's private
  //     64-elem block (in-wave DS ordering, KwS precedent); barrier only cross-wave steps.
  //     volatile blocks register-caching of LDS across steps. ---
  {
    volatile u64* vmain = mainL;
    for (int k2 = 2; k2 <= 1024; k2 <<= 1){
      for (int j = k2 >> 1; j > 0; j >>= 1){
        if (j >= 64 || (j == 32 && k2 >= 128)) __syncthreads();
        int i = tid, ixj = i ^ j;
        if (ixj > i){
          u64 a = vmain[i], b = vmain[ixj];
          bool up = (i & k2) == 0;
          if ((a > b) == up){ vmain[i] = b; vmain[ixj] = a; }
        }
      }
    }
  }
  __syncthreads();
  // --- decode + clip + valid + sigmoid + okey ---
  int r = tid, t = g*1024 + r;
  if (r < k){
    int idx = (int)(mainL[r] & 0xFFFFFFu);
    float4 a = anchors[idx];
    float4 d = deltas[img*R_TOT + idx];
    float o = obj[img*R_TOT + idx];
    float wa = fsub_(a.z, a.x), ha = fsub_(a.w, a.y);
    float cxa = fadd_(a.x, fmul_(0.5f, wa)), cya = fadd_(a.y, fmul_(0.5f, ha));
    float dw = fminf(d.z, BBOX_CLIP), dh = fminf(d.w, BBOX_CLIP);
    float cx = fadd_(fmul_(d.x, wa), cxa), cy = fadd_(fmul_(d.y, ha), cya);
    float w  = fmul_(expf(dw), wa),        h  = fmul_(expf(dh), ha);
    float x1 = fsub_(cx, fmul_(0.5f, w)), y1 = fsub_(cy, fmul_(0.5f, h));
    float x2 = fadd_(cx, fmul_(0.5f, w)), y2 = fadd_(cy, fmul_(0.5f, h));
    x1 = fminf(fmaxf(x1, 0.0f), IMG_SZ); y1 = fminf(fmaxf(y1, 0.0f), IMG_SZ);
    x2 = fminf(fmaxf(x2, 0.0f), IMG_SZ); y2 = fminf(fmaxf(y2, 0.0f), IMG_SZ);
    bool valid = (fsub_(x2, x1) >= 1e-3f) && (fsub_(y2, y1) >= 1e-3f);
    float e = expf(-o);
    float sig = __fdiv_rn(1.0f, fadd_(1.0f, e));
    float s = valid ? sig : -1.0f;
    u32 sb = __float_as_uint(s);
    u32 ms = (sb & 0x80000000u) ? ~sb : (sb | 0x80000000u);
    float4 b4 = make_float4(x1, y1, x2, y2);
    boxL[t] = b4;
    scoreL[t] = sig;
    lokey[r] = (((u64)(~ms)) << 32) | (u32)(lvl*1000 + r);
    lbox[r] = b4;
    lval[r] = valid ? 1 : 0;
  } else {
    lval[r] = 0;
  }
  __syncthreads();
  if (tid < 64){
    int cnt = 0;
    float off = (float)lvl * 801.0f;
    for (int base = 0; base < k; base += 64){
      int r2 = base + lane;
      bool v = (r2 < k) && lval[r2];
      float4 b = lbox[r2 < k ? r2 : 0];
      u64 mask = __ballot(v);
      int before = __popcll(mask & ((1ull << lane) - 1ull));
      if (v){
        int pos = cnt + before;
        nbox[g*1024 + pos] = make_float4(fadd_(b.x,off), fadd_(b.y,off), fadd_(b.z,off), fadd_(b.w,off));
        okeyN[g*1024 + pos] = lokey[r2];
      }
      cnt += __popcll(mask);
    }
    if (lane == 0) ncnt[g] = cnt;
  }
}

// ---------- 3. IoU bitmask (wide): row-major LTG2[row*16+q], diag slot 15 (r10-verbatim) ----------
__global__ __launch_bounds__(64) void k_mask(const float4* __restrict__ nbox,
                                             const int* __restrict__ ncnt,
                                             u64* LTG2){
  int g = blockIdx.x, tr = blockIdx.y, tw = blockIdx.z;
  if (tw > tr) return;
  int m = ncnt[g];
  if (tr*64 >= m) return;
  __shared__ float4 shb[64];
  __shared__ float sharea[64];
  int lane = threadIdx.x;
  if (tw*64 + lane < m){
    float4 b = nbox[g*1024 + tw*64 + lane];
    shb[lane] = b;
    sharea[lane] = fmul_(fsub_(b.z,b.x), fsub_(b.w,b.y));
  }
  __syncthreads();
  int j = tr*64 + lane;
  if (j >= m) return;
  float4 a = nbox[g*1024 + j];
  float areaA = fmul_(fsub_(a.z,a.x), fsub_(a.w,a.y));
  int imax = m - tw*64; if (imax > 64) imax = 64;
  if (tw == tr){
    u64 bitsF = 0;
    for (int ii = lane+1; ii < imax; ii++){
      float4 b = shb[ii];
      float ltx = fmaxf(a.x, b.x), lty = fmaxf(a.y, b.y);
      float rbx = fminf(a.z, b.z), rby = fminf(a.w, b.w);
      float wx = fmaxf(fsub_(rbx, ltx), 0.0f), wy = fmaxf(fsub_(rby, lty), 0.0f);
      float inter = fmul_(wx, wy);
      float den = fadd_(fsub_(fadd_(areaA, sharea[ii]), inter), 1e-9f);
      if (__fdiv_rn(inter, den) > NMS_TH) bitsF |= (1ull << ii);
    }
    LTG2[((size_t)(g*1024 + j))*16 + 15] = bitsF;
  } else {
    u64 bits = 0;
    for (int ii = 0; ii < imax; ii++){
      float4 b = shb[ii];
      float ltx = fmaxf(a.x, b.x), lty = fmaxf(a.y, b.y);
      float rbx = fminf(a.z, b.z), rby = fminf(a.w, b.w);
      float wx = fmaxf(fsub_(rbx, ltx), 0.0f), wy = fmaxf(fsub_(rby, lty), 0.0f);
      float inter = fmul_(wx, wy);
      float den = fadd_(fsub_(fadd_(areaA, sharea[ii]), inter), 1e-9f);
      if (__fdiv_rn(inter, den) > NMS_TH) bits |= (1ull << ii);
    }
    LTG2[((size_t)(g*1024 + j))*16 + tw] = bits;
  }
}

struct ChunkBuf {
  ulonglong2 v0, v1, v2, v3, v4, v5, v6, v7;   // 16 u64: words 0..14 + diagF (slot 15)
  u64 ok;
};

__device__ __forceinline__ void issue_chunk(const u64* __restrict__ LT2,
                                            const u64* __restrict__ oK,
                                            int c, int lane, ChunkBuf& b){
  int row = c*64 + lane;
  const ulonglong2* rp = (const ulonglong2*)(LT2 + (size_t)row*16);
  b.v0 = rp[0]; b.v1 = rp[1]; b.v2 = rp[2]; b.v3 = rp[3];
  b.v4 = rp[4]; b.v5 = rp[5]; b.v6 = rp[6]; b.v7 = rp[7];
  b.ok = oK[row];
}

__device__ __forceinline__ void consume_chunk(const ChunkBuf& b, int c, int m, int lane,
                                              u64* KwR, u64* runsL, int& cnt){
  int row = c*64 + lane;
  bool inr = row < m;
  u64 supp = 0;
  #define TERM(q, val) supp |= (((q) < c) ? (val) : 0ull) & KwR[q];
  TERM(0,  b.v0.x) TERM(1,  b.v0.y) TERM(2,  b.v1.x) TERM(3,  b.v1.y)
  TERM(4,  b.v2.x) TERM(5,  b.v2.y) TERM(6,  b.v3.x) TERM(7,  b.v3.y)
  TERM(8,  b.v4.x) TERM(9,  b.v4.y) TERM(10, b.v5.x) TERM(11, b.v5.y)
  TERM(12, b.v6.x) TERM(13, b.v6.y) TERM(14, b.v7.x)
  #undef TERM
  u64 fwd = inr ? b.v7.y : 0;
  u64 live = __ballot(inr && (supp == 0));
  u64 fz = __ballot(fwd != 0);
  u64 kept = 0;
  while (1){
    u64 lf = live & fz;
    if (!lf){ kept |= live; break; }       // remaining live lanes suppress nobody
    int i = __builtin_ctzll(lf);
    u64 bi = 1ull << i;
    u64 below = live & (bi - 1ull);        // live lanes before i: fwd==0, batch-keep
    kept |= below | bi;
    live &= ~(below | bi);
    live &= ~readlane64(fwd, i);
  }
  KwR[c] = kept;                            // uniform; in-wave DS ordering suffices
  bool kp = (kept >> lane) & 1ull;
  int before = __popcll(kept & ((1ull << lane) - 1ull));
  if (kp) runsL[cnt + before] = b.ok;
  cnt += __popcll(kept);
}

// ---------- 4. fused greedy scan + merge (r10-verbatim) ----------
__global__ __launch_bounds__(1024) void k_scanmerge(const u64* __restrict__ LTG2,
                                                    const int* __restrict__ ncnt,
                                                    const u64* __restrict__ okeyN,
                                                    const float4* __restrict__ boxL,
                                                    const float* __restrict__ scoreL,
                                                    float* out){
  int img = blockIdx.x, tid = threadIdx.x, lane = tid & 63, wid = tid >> 6;
  __shared__ u64 runs[5*1024];
  __shared__ u64 Kw[5][16];
  __shared__ int cl[5];
  if (wid < 5){
    int l = wid, g = img*5 + l;
    int m = ncnt[g];
    int nch = (m + 63) >> 6;
    const u64* LT2 = LTG2 + ((size_t)g*1024)*16;
    const u64* oK = okeyN + g*1024;
    u64* KwR = &Kw[l][0];
    u64* runsL = &runs[l*1024];
    int cnt = 0;
    ChunkBuf A, B;
    if (nch > 0){
      issue_chunk(LT2, oK, 0, lane, A);
      int c = 0;
      while (c < nch){
        if (c+1 < nch) issue_chunk(LT2, oK, c+1, lane, B);
        consume_chunk(A, c, m, lane, KwR, runsL, cnt);
        c++;
        if (c >= nch) break;
        if (c+1 < nch) issue_chunk(LT2, oK, c+1, lane, A);
        consume_chunk(B, c, m, lane, KwR, runsL, cnt);
        c++;
      }
    }
    if (lane == 0) cl[l] = cnt;
  } else {
    for (int t = tid - 320; t < POST; t += 704){
      out[img*POST*4 + t*4 + 0] = 0.0f;
      out[img*POST*4 + t*4 + 1] = 0.0f;
      out[img*POST*4 + t*4 + 2] = 0.0f;
      out[img*POST*4 + t*4 + 3] = 0.0f;
      out[2*POST*4 + img*POST + t] = -1.0f;
    }
  }
  __syncthreads();
  for (int idx = tid; idx < 5*1024; idx += 1024){
    int l = idx >> 10, i = idx & 1023;
    if (i < cl[l]){
      u64 key = runs[l*1024 + i];
      int o0 = l+1; if (o0 >= 5) o0 -= 5;
      int o1 = l+2; if (o1 >= 5) o1 -= 5;
      int o2 = l+3; if (o2 >= 5) o2 -= 5;
      int o3 = l+4; if (o3 >= 5) o3 -= 5;
      const u64* r0 = runs + (o0 << 10);
      const u64* r1 = runs + (o1 << 10);
      const u64* r2 = runs + (o2 << 10);
      const u64* r3 = runs + (o3 << 10);
      int lo0 = 0, hi0 = cl[o0];
      int lo1 = 0, hi1 = cl[o1];
      int lo2 = 0, hi2 = cl[o2];
      int lo3 = 0, hi3 = cl[o3];
      #pragma unroll 1
      for (int st = 0; st < 11; st++){
        int m0 = (lo0+hi0)>>1, m1 = (lo1+hi1)>>1, m2 = (lo2+hi2)>>1, m3 = (lo3+hi3)>>1;
        u64 a0 = r0[m0], a1 = r1[m1], a2 = r2[m2], a3 = r3[m3];
        if (lo0 < hi0){ if (a0 < key) lo0 = m0+1; else hi0 = m0; }
        if (lo1 < hi1){ if (a1 < key) lo1 = m1+1; else hi1 = m1; }
        if (lo2 < hi2){ if (a2 < key) lo2 = m2+1; else hi2 = m2; }
        if (lo3 < hi3){ if (a3 < key) lo3 = m3+1; else hi3 = m3; }
      }
      int rank = i + lo0 + lo1 + lo2 + lo3;
      if (rank < POST){
        int pos = (int)(key & 0xFFFFFFFFull);
        int lvl = pos / 1000, r = pos - lvl*1000;
        int gg = img*5 + lvl;
        float4 bo = boxL[gg*1024 + r];
        float sc = scoreL[gg*1024 + r];
        out[img*POST*4 + rank*4 + 0] = bo.x;
        out[img*POST*4 + rank*4 + 1] = bo.y;
        out[img*POST*4 + rank*4 + 2] = bo.z;
        out[img*POST*4 + rank*4 + 3] = bo.w;
        out[2*POST*4 + img*POST + rank] = sc;
      }
    }
  }
}

extern "C" void kernel_launch(void* const* d_in, const int* in_sizes, int n_in,
                              void* d_out, int out_size, void* d_ws, size_t ws_size,
                              hipStream_t stream){
  (void)in_sizes; (void)n_in; (void)out_size; (void)ws_size;
  const float*  obj     = (const float*)d_in[0];
  const float4* deltas  = (const float4*)d_in[1];
  const float4* anchors = (const float4*)d_in[2];
  float* out = (float*)d_out;
  char* ws = (char*)d_ws;
  int* histS   = (int*)(ws + 0);           // 160*4096 int   -> 2621440
  u64* mainS   = (u64*)(ws + 2621440);     // 160*1024 u64   -> 3932160
  u64* tieS    = (u64*)(ws + 3932160);     // 160*1024 u64   -> 5242880
  int* cntS    = (int*)(ws + 5242880);     // 160 int        -> 5243520
  int* cnt2S   = (int*)(ws + 5243520);     // 160 int        -> 5244160
  float4* boxL = (float4*)(ws + 5244160);  // 10*1024 f4     -> 5408000
  float* scoreL= (float*)(ws + 5408000);   // 10*1024 f32    -> 5448960
  u64* okeyN   = (u64*)(ws + 5448960);     // 10*1024 u64    -> 5530880
  float4* nbox = (float4*)(ws + 5530880);  // 10*1024 f4     -> 5694720
  u64* LTG2    = (u64*)(ws + 5694720);     // 10*1024*16 u64 -> 7005440
  int* ncnt    = (int*)(ws + 7005440);     // 10 int

  {
    dim3 gf(10, 16);
    k_front<<<gf, 256, 0, stream>>>(obj, histS, mainS, tieS, cntS, cnt2S);
  }
  k_seldecode<<<10, 1024, 0, stream>>>(obj, deltas, anchors, histS, mainS, tieS, cntS, cnt2S,
                                       boxL, scoreL, nbox, okeyN, ncnt);
  {
    dim3 gm(10, 16, 16);
    k_mask<<<gm, 64, 0, stream>>>(nbox, ncnt, LTG2);
  }
  k_scanmerge<<<2, 1024, 0, stream>>>(LTG2, ncnt, okeyN, boxL, scoreL, out);
}

// Round 18
// 154.291 us; speedup vs baseline: 1.0795x; 1.0795x over previous
//
#include <hip/hip_runtime.h>

typedef unsigned long long u64;
typedef unsigned int u32;

#define R_TOT 159882
#define POST 1000
#define IMG_SZ 800.0f
#define NMS_TH 0.7f
#define BBOX_CLIP 4.135166556742356f
#define LCAP 1024

__device__ __forceinline__ float fadd_(float a, float b){ return __fadd_rn(a,b); }
__device__ __forceinline__ float fsub_(float a, float b){ return __fsub_rn(a,b); }
__device__ __forceinline__ float fmul_(float a, float b){ return __fmul_rn(a,b); }

__device__ __forceinline__ int lvl_len(int l){ const int L[5]={120000,30000,7500,1875,507}; return L[l]; }
__device__ __forceinline__ int lvl_off(int l){ const int L[5]={0,120000,150000,157500,159375}; return L[l]; }
__device__ __forceinline__ int lvl_k(int l){ const int L[5]={1000,1000,1000,1000,507}; return L[l]; }

__device__ __forceinline__ u32 mono_(u32 u){ return (u & 0x80000000u) ? ~u : (u | 0x80000000u); }

__device__ __forceinline__ u64 readlane64(u64 v, int i){
  u32 lo = (u32)__builtin_amdgcn_readlane((int)(u32)v, i);
  u32 hi = (u32)__builtin_amdgcn_readlane((int)(u32)(v >> 32), i);
  return ((u64)hi << 32) | (u64)lo;
}

// ---------- 1. k_front: per-slice hist (published) + LOCAL pick + collect (r16-verbatim) ----------
__global__ __launch_bounds__(256) void k_front(const float* __restrict__ obj,
                                               int* histS,
                                               u64* mainS, u64* tieS,
                                               int* cntS, int* cnt2S){
  int g = blockIdx.x, sl = blockIdx.y;
  int img = g/5, lvl = g%5;
  int n = lvl_len(lvl), s0 = lvl_off(lvl), k = lvl_k(lvl);
  int tid = threadIdx.x, lane = tid & 63, wid = tid >> 6;
  __shared__ __align__(16) int lh[4096];
  __shared__ int wsum[4];
  __shared__ int sh_bs, lc, lc2;
  for (int i = tid; i < 4096; i += 256) lh[i] = 0;
  __syncthreads();
  int lo = (int)((long long)n * sl / 16), hiS = (int)((long long)n * (sl+1) / 16);
  int ns = hiS - lo;
  int ks = k < ns ? k : ns;
  const float* p = obj + img*R_TOT + s0;
  #pragma unroll 4
  for (int e = lo + tid; e < hiS; e += 256){
    u32 mu = mono_(__float_as_uint(p[e]));
    atomicAdd(&lh[(~mu) >> 20], 1);
  }
  __syncthreads();
  {
    int* dst = histS + (g*16 + sl)*4096;
    for (int i = tid; i < 4096; i += 256) dst[i] = lh[i];
  }
  int h[16];
  #pragma unroll
  for (int j = 0; j < 16; j++) h[j] = lh[16*tid + j];
  int part = 0;
  #pragma unroll
  for (int j = 0; j < 16; j++) part += h[j];
  int x = part;
  for (int d = 1; d < 64; d <<= 1){ int y = __shfl_up(x, d); if (lane >= d) x += y; }
  if (lane == 63) wsum[wid] = x;
  if (tid == 0){ lc = 0; lc2 = 0; }
  __syncthreads();
  int add = 0;
  for (int w = 0; w < wid; w++) add += wsum[w];
  int incl = x + add, excl = incl - part;
  if (excl < ks && ks <= incl){
    int cum = excl;
    #pragma unroll
    for (int q = 0; q < 16; q++){
      if (cum + h[q] >= ks){ sh_bs = 16*tid + q; break; }
      cum += h[q];
    }
  }
  __syncthreads();
  int bs = sh_bs;
  u64* lmain = (u64*)lh;            // [0, 8K)
  u64* ltie  = (u64*)lh + 1024;     // [8K, 16K)
  #pragma unroll 4
  for (int e = lo + tid; e < hiS; e += 256){
    u32 mu = mono_(__float_as_uint(p[e]));
    u64 key56 = (((u64)(~mu)) << 24) | (u32)(s0 + e);
    int bin = (int)(key56 >> 44);
    if (bin < bs){ int pos = atomicAdd(&lc, 1); lmain[pos] = key56; }      // <= ks-1 <= 999
    else if (bin == bs){ int pos = atomicAdd(&lc2, 1); if (pos < 1024) ltie[pos] = key56; }
  }
  __syncthreads();
  int idx16 = g*16 + sl;
  if (tid == 0){ cntS[idx16] = lc; cnt2S[idx16] = lc2; }
  for (int i = tid; i < lc; i += 256) mainS[idx16*1024 + i] = lmain[i];
  int c2l = lc2 < 1024 ? lc2 : 1024;
  for (int i = tid; i < c2l; i += 256) tieS[idx16*1024 + i] = ltie[i];
}

// ---------- 2a. k_selA: pick + gather + tie refine -> selected set (UNORDERED) to selG ----------
__global__ __launch_bounds__(1024) void k_selA(const float* __restrict__ obj,
                                               const int* __restrict__ histS,
                                               const u64* __restrict__ mainS,
                                               const u64* __restrict__ tieS,
                                               const int* __restrict__ cntS,
                                               const int* __restrict__ cnt2S,
                                               u64* selG){
  int g = blockIdx.x, img = g/5, lvl = g%5;
  int s0 = lvl_off(lvl), n = lvl_len(lvl), k = lvl_k(lvl);
  const float* p = obj + img*R_TOT + s0;
  __shared__ u64 Lbuf[LCAP];
  __shared__ u64 mainL[1024];
  __shared__ __align__(16) int chist[4096];   // candidate sub-hist / fallback hist
  __shared__ u64 subT[1024];
  __shared__ int h16[16];
  __shared__ int scnt[16], tcnt[16];
  __shared__ int wsum16[16];
  __shared__ int sh_bs, sh_rem, sh_mc, sh_tc, sh_sc, sh_rem2, sh_ovf;
  __shared__ int sh_bs2, sh_rem2b, sh_c3;
  __shared__ u64 sh_thr;
  int tid = threadIdx.x, lane = tid & 63, wid = tid >> 6;
  if (tid < 16){ scnt[tid] = cntS[g*16 + tid]; tcnt[tid] = cnt2S[g*16 + tid]; }
  mainL[tid] = ~0ull;
  __syncthreads();
  if (tid == 0){
    int o = 0;
    #pragma unroll
    for (int q = 0; q < 16; q++) if (tcnt[q] > 1024) o = 1;
    sh_ovf = o; sh_mc = 0; sh_tc = 0; sh_sc = 0; sh_c3 = 0;
  }
  // exact global pick: sum 16 slice histograms, 4 bins/thread
  int h0 = 0, h1 = 0, h2 = 0, h3 = 0;
  {
    const int* hb = histS + g*16*4096 + 4*tid;
    #pragma unroll
    for (int s2 = 0; s2 < 16; s2++){
      int4 a = *(const int4*)(hb + s2*4096);
      h0 += a.x; h1 += a.y; h2 += a.z; h3 += a.w;
    }
  }
  int part = h0 + h1 + h2 + h3;
  int x = part;
  for (int d = 1; d < 64; d <<= 1){ int y = __shfl_up(x, d); if (lane >= d) x += y; }
  if (lane == 63) wsum16[wid] = x;
  __syncthreads();
  int add = 0;
  for (int w = 0; w < wid; w++) add += wsum16[w];
  int incl = x + add, excl = incl - part;
  if (excl < k && k <= incl){
    int cum = excl;
    if (cum + h0 >= k){ sh_bs = 4*tid;   sh_rem = k - cum; }
    else { cum += h0;
      if (cum + h1 >= k){ sh_bs = 4*tid+1; sh_rem = k - cum; }
      else { cum += h1;
        if (cum + h2 >= k){ sh_bs = 4*tid+2; sh_rem = k - cum; }
        else { cum += h2;    sh_bs = 4*tid+3; sh_rem = k - cum; }
      }
    }
  }
  __syncthreads();
  int bs = sh_bs;
  if (!sh_ovf){
    // wave-per-slice gather, clamped-address 4-deep batching
    int mc = scnt[wid];
    int tcc = tcnt[wid] < 1024 ? tcnt[wid] : 1024;
    const u64* msrc = mainS + ((size_t)(g*16 + wid))*1024;
    const u64* tsrc = tieS + ((size_t)(g*16 + wid))*1024;
    for (int base = 0; base < mc; base += 256){
      int i0 = base + lane;
      u64 v0 = msrc[(i0       < mc) ? i0       : 0];
      u64 v1 = msrc[(i0+64    < mc) ? i0+64    : 0];
      u64 v2 = msrc[(i0+128   < mc) ? i0+128   : 0];
      u64 v3 = msrc[(i0+192   < mc) ? i0+192   : 0];
      #define PUSH(cond, vv) if (cond){ int b_ = (int)((vv) >> 44); \
        if (b_ < bs){ int pos = atomicAdd(&sh_mc, 1); mainL[pos] = (vv); } \
        else if (b_ == bs){ int pos = atomicAdd(&sh_tc, 1); if (pos < LCAP) Lbuf[pos] = (vv); } }
      PUSH(i0 < mc, v0) PUSH(i0+64 < mc, v1) PUSH(i0+128 < mc, v2) PUSH(i0+192 < mc, v3)
    }
    for (int base = 0; base < tcc; base += 256){
      int i0 = base + lane;
      u64 v0 = tsrc[(i0       < tcc) ? i0       : 0];
      u64 v1 = tsrc[(i0+64    < tcc) ? i0+64    : 0];
      u64 v2 = tsrc[(i0+128   < tcc) ? i0+128   : 0];
      u64 v3 = tsrc[(i0+192   < tcc) ? i0+192   : 0];
      PUSH(i0 < tcc, v0) PUSH(i0+64 < tcc, v1) PUSH(i0+128 < tcc, v2) PUSH(i0+192 < tcc, v3)
      #undef PUSH
    }
    __syncthreads();
    int nb = sh_mc, c2r = sh_tc, rem = sh_rem;
    if (c2r <= LCAP){
      // sub-histogram tie refine on bits 43..32 (exact; keys unique)
      for (int i = tid; i < 4096; i += 1024) chist[i] = 0;
      __syncthreads();
      for (int e = tid; e < c2r; e += 1024){
        u64 kk = Lbuf[e];
        atomicAdd(&chist[(int)((kk >> 32) & 0xFFFu)], 1);
      }
      __syncthreads();
      int t0 = chist[4*tid], t1 = chist[4*tid+1], t2 = chist[4*tid+2], t3 = chist[4*tid+3];
      int tpart = t0 + t1 + t2 + t3;
      int tx = tpart;
      for (int d = 1; d < 64; d <<= 1){ int y = __shfl_up(tx, d); if (lane >= d) tx += y; }
      if (lane == 63) wsum16[wid] = tx;
      __syncthreads();
      int tadd = 0;
      for (int w = 0; w < wid; w++) tadd += wsum16[w];
      int tincl = tx + tadd, texcl = tincl - tpart;
      if (texcl < rem && rem <= tincl){
        int cum = texcl;
        if (cum + t0 >= rem){ sh_bs2 = 4*tid;   sh_rem2b = rem - cum; }
        else { cum += t0;
          if (cum + t1 >= rem){ sh_bs2 = 4*tid+1; sh_rem2b = rem - cum; }
          else { cum += t1;
            if (cum + t2 >= rem){ sh_bs2 = 4*tid+2; sh_rem2b = rem - cum; }
            else { cum += t2;    sh_bs2 = 4*tid+3; sh_rem2b = rem - cum; }
          }
        }
      }
      __syncthreads();
      int bs2 = sh_bs2;
      for (int e = tid; e < c2r; e += 1024){
        u64 kk = Lbuf[e];
        int sb2 = (int)((kk >> 32) & 0xFFFu);
        if (sb2 < bs2){ int p2 = atomicAdd(&sh_sc, 1); mainL[nb + p2] = kk; }
        else if (sb2 == bs2){ int p3 = atomicAdd(&sh_c3, 1); subT[p3] = kk; }
      }
      __syncthreads();
      int c3 = sh_c3, rem2b = sh_rem2b;
      for (int e = tid; e < c3; e += 1024){
        u64 kk = subT[e];
        int rk = 0;
        for (int qq = 0; qq < c3; qq++) rk += (subT[qq] < kk) ? 1 : 0;
        if (rk < rem2b){ int p2 = atomicAdd(&sh_sc, 1); mainL[nb + p2] = kk; }
      }
    } else {
      if (tid == 0) sh_ovf = 1;
    }
    __syncthreads();
  }
  if (sh_ovf){
    // FULL FALLBACK from obj (never hit on bench data)
    for (int i = tid; i < 4096; i += 1024) chist[i] = 0;
    if (tid == 0){ sh_mc = 0; sh_sc = 0; }
    __syncthreads();
    for (int e = tid; e < n; e += 1024){
      u32 mu = mono_(__float_as_uint(p[e]));
      atomicAdd(&chist[(int)((~mu) >> 20)], 1);
    }
    __syncthreads();
    int f0 = chist[4*tid], f1 = chist[4*tid+1], f2 = chist[4*tid+2], f3 = chist[4*tid+3];
    int fpart = f0 + f1 + f2 + f3;
    int fx = fpart;
    for (int d = 1; d < 64; d <<= 1){ int y = __shfl_up(fx, d); if (lane >= d) fx += y; }
    if (lane == 63) wsum16[wid] = fx;
    __syncthreads();
    int fadd2 = 0;
    for (int w = 0; w < wid; w++) fadd2 += wsum16[w];
    int fincl = fx + fadd2, fexcl = fincl - fpart;
    if (fexcl < k && k <= fincl){
      int cum = fexcl;
      if (cum + f0 >= k){ sh_bs = 4*tid;   sh_rem = k - cum; }
      else { cum += f0;
        if (cum + f1 >= k){ sh_bs = 4*tid+1; sh_rem = k - cum; }
        else { cum += f1;
          if (cum + f2 >= k){ sh_bs = 4*tid+2; sh_rem = k - cum; }
          else { cum += f2;    sh_bs = 4*tid+3; sh_rem = k - cum; }
        }
      }
    }
    mainL[tid] = ~0ull;
    __syncthreads();
    int fbs = sh_bs;
    for (int e = tid; e < n; e += 1024){
      u32 mu = mono_(__float_as_uint(p[e]));
      u64 kk = (((u64)(~mu)) << 24) | (u32)(s0 + e);
      if ((int)(kk >> 44) < fbs){ int pos = atomicAdd(&sh_mc, 1); mainL[pos] = kk; }
    }
    __syncthreads();
    int nb = sh_mc;
    if (tid == 0){ sh_thr = ((u64)fbs) << 44; sh_rem2 = sh_rem; }
    __syncthreads();
    for (int shift = 40; shift >= 0; shift -= 4){
      if (tid < 16) h16[tid] = 0;
      __syncthreads();
      u64 pref = sh_thr;
      u64 himask = ~((1ull << (shift+4)) - 1ull);
      for (int e = tid; e < n; e += 1024){
        u32 mu = mono_(__float_as_uint(p[e]));
        u64 kk = (((u64)(~mu)) << 24) | (u32)(s0 + e);
        if ((kk & himask) == (pref & himask)) atomicAdd(&h16[(int)((kk >> shift) & 15)], 1);
      }
      __syncthreads();
      if (tid == 0){
        int r2 = sh_rem2, cum = 0;
        for (int d = 0; d < 16; d++){
          int hb2 = h16[d];
          if (cum + hb2 >= r2){ sh_thr = pref | ((u64)d << shift); sh_rem2 = r2 - cum; break; }
          cum += hb2;
        }
      }
      __syncthreads();
    }
    u64 thr = sh_thr;
    for (int e = tid; e < n; e += 1024){
      u32 mu = mono_(__float_as_uint(p[e]));
      u64 kk = (((u64)(~mu)) << 24) | (u32)(s0 + e);
      if ((int)(kk >> 44) == sh_bs && kk <= thr){ int p2 = atomicAdd(&sh_sc, 1); mainL[nb + p2] = kk; }
    }
    __syncthreads();
  }
  selG[g*1024 + tid] = mainL[tid];   // unordered selected set (+ ~0 padding)
}

// ---------- 2b. k_selB: load selected set, sort, decode, compact ----------
__global__ __launch_bounds__(1024) void k_selB(const float* __restrict__ obj,
                                               const float4* __restrict__ deltas,
                                               const float4* __restrict__ anchors,
                                               const u64* __restrict__ selG,
                                               float4* boxL, float* scoreL,
                                               float4* nbox, u64* okeyN, int* ncnt){
  int g = blockIdx.x, img = g/5, lvl = g%5;
  int k = lvl_k(lvl);
  __shared__ u64 mainL[1024];
  __shared__ float4 lbox[1024];
  __shared__ u64 lokey[1024];
  __shared__ unsigned char lval[1024];
  int tid = threadIdx.x, lane = tid & 63;
  mainL[tid] = selG[g*1024 + tid];
  __syncthreads();
  // bitonic sort 1024 (plain r16: conflict-free consecutive-index)
  for (int k2 = 2; k2 <= 1024; k2 <<= 1){
    for (int j = k2 >> 1; j > 0; j >>= 1){
      __syncthreads();
      int i = tid, ixj = i ^ j;
      if (ixj > i){
        u64 a = mainL[i], b = mainL[ixj];
        bool up = (i & k2) == 0;
        if ((a > b) == up){ mainL[i] = b; mainL[ixj] = a; }
      }
    }
  }
  __syncthreads();
  int r = tid, t = g*1024 + r;
  if (r < k){
    int idx = (int)(mainL[r] & 0xFFFFFFu);
    float4 a = anchors[idx];
    float4 d = deltas[img*R_TOT + idx];
    float o = obj[img*R_TOT + idx];
    float wa = fsub_(a.z, a.x), ha = fsub_(a.w, a.y);
    float cxa = fadd_(a.x, fmul_(0.5f, wa)), cya = fadd_(a.y, fmul_(0.5f, ha));
    float dw = fminf(d.z, BBOX_CLIP), dh = fminf(d.w, BBOX_CLIP);
    float cx = fadd_(fmul_(d.x, wa), cxa), cy = fadd_(fmul_(d.y, ha), cya);
    float w  = fmul_(expf(dw), wa),        h  = fmul_(expf(dh), ha);
    float x1 = fsub_(cx, fmul_(0.5f, w)), y1 = fsub_(cy, fmul_(0.5f, h));
    float x2 = fadd_(cx, fmul_(0.5f, w)), y2 = fadd_(cy, fmul_(0.5f, h));
    x1 = fminf(fmaxf(x1, 0.0f), IMG_SZ); y1 = fminf(fmaxf(y1, 0.0f), IMG_SZ);
    x2 = fminf(fmaxf(x2, 0.0f), IMG_SZ); y2 = fminf(fmaxf(y2, 0.0f), IMG_SZ);
    bool valid = (fsub_(x2, x1) >= 1e-3f) && (fsub_(y2, y1) >= 1e-3f);
    float e = expf(-o);
    float sig = __fdiv_rn(1.0f, fadd_(1.0f, e));
    float s = valid ? sig : -1.0f;
    u32 sb = __float_as_uint(s);
    u32 ms = (sb & 0x80000000u) ? ~sb : (sb | 0x80000000u);
    float4 b4 = make_float4(x1, y1, x2, y2);
    boxL[t] = b4;
    scoreL[t] = sig;
    lokey[r] = (((u64)(~ms)) << 32) | (u32)(lvl*1000 + r);
    lbox[r] = b4;
    lval[r] = valid ? 1 : 0;
  } else {
    lval[r] = 0;
  }
  __syncthreads();
  if (tid < 64){
    int cnt = 0;
    float off = (float)lvl * 801.0f;
    for (int base = 0; base < k; base += 64){
      int r2 = base + lane;
      bool v = (r2 < k) && lval[r2];
      float4 b = lbox[r2 < k ? r2 : 0];
      u64 mask = __ballot(v);
      int before = __popcll(mask & ((1ull << lane) - 1ull));
      if (v){
        int pos = cnt + before;
        nbox[g*1024 + pos] = make_float4(fadd_(b.x,off), fadd_(b.y,off), fadd_(b.z,off), fadd_(b.w,off));
        okeyN[g*1024 + pos] = lokey[r2];
      }
      cnt += __popcll(mask);
    }
    if (lane == 0) ncnt[g] = cnt;
  }
}

// ---------- 3. IoU bitmask (wide): row-major LTG2[row*16+q], diag slot 15 (r10-verbatim) ----------
__global__ __launch_bounds__(64) void k_mask(const float4* __restrict__ nbox,
                                             const int* __restrict__ ncnt,
                                             u64* LTG2){
  int g = blockIdx.x, tr = blockIdx.y, tw = blockIdx.z;
  if (tw > tr) return;
  int m = ncnt[g];
  if (tr*64 >= m) return;
  __shared__ float4 shb[64];
  __shared__ float sharea[64];
  int lane = threadIdx.x;
  if (tw*64 + lane < m){
    float4 b = nbox[g*1024 + tw*64 + lane];
    shb[lane] = b;
    sharea[lane] = fmul_(fsub_(b.z,b.x), fsub_(b.w,b.y));
  }
  __syncthreads();
  int j = tr*64 + lane;
  if (j >= m) return;
  float4 a = nbox[g*1024 + j];
  float areaA = fmul_(fsub_(a.z,a.x), fsub_(a.w,a.y));
  int imax = m - tw*64; if (imax > 64) imax = 64;
  if (tw == tr){
    u64 bitsF = 0;
    for (int ii = lane+1; ii < imax; ii++){
      float4 b = shb[ii];
      float ltx = fmaxf(a.x, b.x), lty = fmaxf(a.y, b.y);
      float rbx = fminf(a.z, b.z), rby = fminf(a.w, b.w);
      float wx = fmaxf(fsub_(rbx, ltx), 0.0f), wy = fmaxf(fsub_(rby, lty), 0.0f);
      float inter = fmul_(wx, wy);
      float den = fadd_(fsub_(fadd_(areaA, sharea[ii]), inter), 1e-9f);
      if (__fdiv_rn(inter, den) > NMS_TH) bitsF |= (1ull << ii);
    }
    LTG2[((size_t)(g*1024 + j))*16 + 15] = bitsF;
  } else {
    u64 bits = 0;
    for (int ii = 0; ii < imax; ii++){
      float4 b = shb[ii];
      float ltx = fmaxf(a.x, b.x), lty = fmaxf(a.y, b.y);
      float rbx = fminf(a.z, b.z), rby = fminf(a.w, b.w);
      float wx = fmaxf(fsub_(rbx, ltx), 0.0f), wy = fmaxf(fsub_(rby, lty), 0.0f);
      float inter = fmul_(wx, wy);
      float den = fadd_(fsub_(fadd_(areaA, sharea[ii]), inter), 1e-9f);
      if (__fdiv_rn(inter, den) > NMS_TH) bits |= (1ull << ii);
    }
    LTG2[((size_t)(g*1024 + j))*16 + tw] = bits;
  }
}

struct ChunkBuf {
  ulonglong2 v0, v1, v2, v3, v4, v5, v6, v7;   // 16 u64: words 0..14 + diagF (slot 15)
  u64 ok;
};

__device__ __forceinline__ void issue_chunk(const u64* __restrict__ LT2,
                                            const u64* __restrict__ oK,
                                            int c, int lane, ChunkBuf& b){
  int row = c*64 + lane;
  const ulonglong2* rp = (const ulonglong2*)(LT2 + (size_t)row*16);
  b.v0 = rp[0]; b.v1 = rp[1]; b.v2 = rp[2]; b.v3 = rp[3];
  b.v4 = rp[4]; b.v5 = rp[5]; b.v6 = rp[6]; b.v7 = rp[7];
  b.ok = oK[row];
}

__device__ __forceinline__ void consume_chunk(const ChunkBuf& b, int c, int m, int lane,
                                              u64* KwR, u64* runsL, int& cnt){
  int row = c*64 + lane;
  bool inr = row < m;
  u64 supp = 0;
  #define TERM(q, val) supp |= (((q) < c) ? (val) : 0ull) & KwR[q];
  TERM(0,  b.v0.x) TERM(1,  b.v0.y) TERM(2,  b.v1.x) TERM(3,  b.v1.y)
  TERM(4,  b.v2.x) TERM(5,  b.v2.y) TERM(6,  b.v3.x) TERM(7,  b.v3.y)
  TERM(8,  b.v4.x) TERM(9,  b.v4.y) TERM(10, b.v5.x) TERM(11, b.v5.y)
  TERM(12, b.v6.x) TERM(13, b.v6.y) TERM(14, b.v7.x)
  #undef TERM
  u64 fwd = inr ? b.v7.y : 0;
  u64 live = __ballot(inr && (supp == 0));
  u64 fz = __ballot(fwd != 0);
  u64 kept = 0;
  while (1){
    u64 lf = live & fz;
    if (!lf){ kept |= live; break; }       // remaining live lanes suppress nobody
    int i = __builtin_ctzll(lf);
    u64 bi = 1ull << i;
    u64 below = live & (bi - 1ull);        // live lanes before i: fwd==0, batch-keep
    kept |= below | bi;
    live &= ~(below | bi);
    live &= ~readlane64(fwd, i);
  }
  KwR[c] = kept;                            // uniform; in-wave DS ordering suffices
  bool kp = (kept >> lane) & 1ull;
  int before = __popcll(kept & ((1ull << lane) - 1ull));
  if (kp) runsL[cnt + before] = b.ok;
  cnt += __popcll(kept);
}

// ---------- 4. fused greedy scan + merge (r10-verbatim) ----------
__global__ __launch_bounds__(1024) void k_scanmerge(const u64* __restrict__ LTG2,
                                                    const int* __restrict__ ncnt,
                                                    const u64* __restrict__ okeyN,
                                                    const float4* __restrict__ boxL,
                                                    const float* __restrict__ scoreL,
                                                    float* out){
  int img = blockIdx.x, tid = threadIdx.x, lane = tid & 63, wid = tid >> 6;
  __shared__ u64 runs[5*1024];
  __shared__ u64 Kw[5][16];
  __shared__ int cl[5];
  if (wid < 5){
    int l = wid, g = img*5 + l;
    int m = ncnt[g];
    int nch = (m + 63) >> 6;
    const u64* LT2 = LTG2 + ((size_t)g*1024)*16;
    const u64* oK = okeyN + g*1024;
    u64* KwR = &Kw[l][0];
    u64* runsL = &runs[l*1024];
    int cnt = 0;
    ChunkBuf A, B;
    if (nch > 0){
      issue_chunk(LT2, oK, 0, lane, A);
      int c = 0;
      while (c < nch){
        if (c+1 < nch) issue_chunk(LT2, oK, c+1, lane, B);
        consume_chunk(A, c, m, lane, KwR, runsL, cnt);
        c++;
        if (c >= nch) break;
        if (c+1 < nch) issue_chunk(LT2, oK, c+1, lane, A);
        consume_chunk(B, c, m, lane, KwR, runsL, cnt);
        c++;
      }
    }
    if (lane == 0) cl[l] = cnt;
  } else {
    for (int t = tid - 320; t < POST; t += 704){
      out[img*POST*4 + t*4 + 0] = 0.0f;
      out[img*POST*4 + t*4 + 1] = 0.0f;
      out[img*POST*4 + t*4 + 2] = 0.0f;
      out[img*POST*4 + t*4 + 3] = 0.0f;
      out[2*POST*4 + img*POST + t] = -1.0f;
    }
  }
  __syncthreads();
  for (int idx = tid; idx < 5*1024; idx += 1024){
    int l = idx >> 10, i = idx & 1023;
    if (i < cl[l]){
      u64 key = runs[l*1024 + i];
      int o0 = l+1; if (o0 >= 5) o0 -= 5;
      int o1 = l+2; if (o1 >= 5) o1 -= 5;
      int o2 = l+3; if (o2 >= 5) o2 -= 5;
      int o3 = l+4; if (o3 >= 5) o3 -= 5;
      const u64* r0 = runs + (o0 << 10);
      const u64* r1 = runs + (o1 << 10);
      const u64* r2 = runs + (o2 << 10);
      const u64* r3 = runs + (o3 << 10);
      int lo0 = 0, hi0 = cl[o0];
      int lo1 = 0, hi1 = cl[o1];
      int lo2 = 0, hi2 = cl[o2];
      int lo3 = 0, hi3 = cl[o3];
      #pragma unroll 1
      for (int st = 0; st < 11; st++){
        int m0 = (lo0+hi0)>>1, m1 = (lo1+hi1)>>1, m2 = (lo2+hi2)>>1, m3 = (lo3+hi3)>>1;
        u64 a0 = r0[m0], a1 = r1[m1], a2 = r2[m2], a3 = r3[m3];
        if (lo0 < hi0){ if (a0 < key) lo0 = m0+1; else hi0 = m0; }
        if (lo1 < hi1){ if (a1 < key) lo1 = m1+1; else hi1 = m1; }
        if (lo2 < hi2){ if (a2 < key) lo2 = m2+1; else hi2 = m2; }
        if (lo3 < hi3){ if (a3 < key) lo3 = m3+1; else hi3 = m3; }
      }
      int rank = i + lo0 + lo1 + lo2 + lo3;
      if (rank < POST){
        int pos = (int)(key & 0xFFFFFFFFull);
        int lvl = pos / 1000, r = pos - lvl*1000;
        int gg = img*5 + lvl;
        float4 bo = boxL[gg*1024 + r];
        float sc = scoreL[gg*1024 + r];
        out[img*POST*4 + rank*4 + 0] = bo.x;
        out[img*POST*4 + rank*4 + 1] = bo.y;
        out[img*POST*4 + rank*4 + 2] = bo.z;
        out[img*POST*4 + rank*4 + 3] = bo.w;
        out[2*POST*4 + img*POST + rank] = sc;
      }
    }
  }
}

extern "C" void kernel_launch(void* const* d_in, const int* in_sizes, int n_in,
                              void* d_out, int out_size, void* d_ws, size_t ws_size,
                              hipStream_t stream){
  (void)in_sizes; (void)n_in; (void)out_size; (void)ws_size;
  const float*  obj     = (const float*)d_in[0];
  const float4* deltas  = (const float4*)d_in[1];
  const float4* anchors = (const float4*)d_in[2];
  float* out = (float*)d_out;
  char* ws = (char*)d_ws;
  int* histS   = (int*)(ws + 0);           // 160*4096 int   -> 2621440
  u64* mainS   = (u64*)(ws + 2621440);     // 160*1024 u64   -> 3932160
  u64* tieS    = (u64*)(ws + 3932160);     // 160*1024 u64   -> 5242880
  int* cntS    = (int*)(ws + 5242880);     // 160 int        -> 5243520
  int* cnt2S   = (int*)(ws + 5243520);     // 160 int        -> 5244160
  float4* boxL = (float4*)(ws + 5244160);  // 10*1024 f4     -> 5408000
  float* scoreL= (float*)(ws + 5408000);   // 10*1024 f32    -> 5448960
  u64* okeyN   = (u64*)(ws + 5448960);     // 10*1024 u64    -> 5530880
  float4* nbox = (float4*)(ws + 5530880);  // 10*1024 f4     -> 5694720
  u64* LTG2    = (u64*)(ws + 5694720);     // 10*1024*16 u64 -> 7005440
  int* ncnt    = (int*)(ws + 7005440);     // 10 int         -> 7005480 (pad 7005504)
  u64* selG    = (u64*)(ws + 7005504);     // 10*1024 u64    -> 7087424

  {
    dim3 gf(10, 16);
    k_front<<<gf, 256, 0, stream>>>(obj, histS, mainS, tieS, cntS, cnt2S);
  }
  k_selA<<<10, 1024, 0, stream>>>(obj, histS, mainS, tieS, cntS, cnt2S, selG);
  k_selB<<<10, 1024, 0, stream>>>(obj, deltas, anchors, selG, boxL, scoreL, nbox, okeyN, ncnt);
  {
    dim3 gm(10, 16, 16);
    k_mask<<<gm, 64, 0, stream>>>(nbox, ncnt, LTG2);
  }
  k_scanmerge<<<2, 1024, 0, stream>>>(LTG2, ncnt, okeyN, boxL, scoreL, out);
}